// Round 3
// baseline (98.318 us; speedup 1.0000x reference)
//
#include <hip/hip_runtime.h>

// PIQuantumDQN: 4-qubit, 5-layer re-uploading circuit, B=524288 samples.
// One thread per sample; the 16-amplitude complex state lives in registers.
// wire q (0 = MSB) <-> bit (3-q) of the flat index, so mask(q) = 8 >> q.
// All I/O is float32 (threshold arithmetic proves _any_bf16 == False:
// the bf16 floor of ~0.031 never bound; printed threshold == 2% relative).

template<int MASK>
__device__ __forceinline__ void apply_ry(float re[16], float im[16], float c, float s) {
#pragma unroll
    for (int i0 = 0; i0 < 16; ++i0) {
        if (i0 & MASK) continue;
        const int i1 = i0 | MASK;
        float r0 = re[i0], r1 = re[i1];
        float m0 = im[i0], m1 = im[i1];
        re[i0] = c * r0 - s * r1;
        re[i1] = s * r0 + c * r1;
        im[i0] = c * m0 - s * m1;
        im[i1] = s * m0 + c * m1;
    }
}

// RX(t): a0' = c*a0 - i*s*a1 ; a1' = -i*s*a0 + c*a1   (c=cos t/2, s=sin t/2)
template<int MASK>
__device__ __forceinline__ void apply_rx(float re[16], float im[16], float c, float s) {
#pragma unroll
    for (int i0 = 0; i0 < 16; ++i0) {
        if (i0 & MASK) continue;
        const int i1 = i0 | MASK;
        float r0 = re[i0], r1 = re[i1];
        float m0 = im[i0], m1 = im[i1];
        re[i0] = c * r0 + s * m1;
        im[i0] = c * m0 - s * r1;
        re[i1] = c * r1 + s * m0;
        im[i1] = c * m1 - s * r0;
    }
}

template<int CMASK, int TMASK>
__device__ __forceinline__ void apply_cnot(float re[16], float im[16]) {
#pragma unroll
    for (int i = 0; i < 16; ++i) {
        if ((i & CMASK) && !(i & TMASK)) {
            const int j = i | TMASK;
            float tr = re[i]; re[i] = re[j]; re[j] = tr;
            float ti = im[i]; im[i] = im[j]; im[j] = ti;
        }
    }
}

__global__ __launch_bounds__(256) void qdqn_kernel(
    const float* __restrict__ x,        // (B,4) fp32
    const float* __restrict__ weights,  // (5,4) fp32
    const float* __restrict__ Wm,       // (2,4) fp32
    const float* __restrict__ bv,       // (2,)  fp32
    float2* __restrict__ out,           // (B,2) fp32
    int B)
{
    __shared__ float wc[20], ws[20];   // cos/sin of weights[l][q]/2
    __shared__ float coef[2][16];      // coef[j][i] = sum_q W[j][q]*Zsign(i,q)
    __shared__ float bsh[2];

    const int tid = threadIdx.x;
    if (tid < 20) {
        float w = weights[tid];
        __sincosf(0.5f * w, &ws[tid], &wc[tid]);
    }
    if (tid < 32) {
        int j = tid >> 4, i = tid & 15;
        float acc = 0.f;
#pragma unroll
        for (int q = 0; q < 4; ++q) {
            float sgn = ((i >> (3 - q)) & 1) ? -1.f : 1.f;
            acc += Wm[j * 4 + q] * sgn;
        }
        coef[j][i] = acc;
    }
    if (tid < 2) bsh[tid] = bv[tid];
    __syncthreads();

    const int b = blockIdx.x * blockDim.x + tid;
    if (b >= B) return;

    // ---- load x (16B coalesced), compute RY half-angle cos/sin ----
    const float4 xraw = ((const float4*)x)[b];
    float xv[4] = { xraw.x, xraw.y, xraw.z, xraw.w };
    const float inv_bounds[4] = { 1.0f / 4.8f, 1.0f / 4.0f, 1.0f / 0.418f, 1.0f / 4.0f };
    const float HALF_PI = 1.57079632679489662f;
    float rc[4], rs[4];
#pragma unroll
    for (int q = 0; q < 4; ++q) {
        float xn = xv[q] * inv_bounds[q];
        xn = fminf(fmaxf(xn, -1.0f), 1.0f);
        __sincosf(xn * HALF_PI, &rs[q], &rc[q]);
    }

    // ---- state in registers ----
    float re[16], im[16];
#pragma unroll
    for (int i = 0; i < 16; ++i) { re[i] = 0.f; im[i] = 0.f; }
    re[0] = 1.0f;

#pragma unroll
    for (int l = 0; l < 5; ++l) {
        // data re-uploading RY embedding
        apply_ry<8>(re, im, rc[0], rs[0]);
        apply_ry<4>(re, im, rc[1], rs[1]);
        apply_ry<2>(re, im, rc[2], rs[2]);
        apply_ry<1>(re, im, rc[3], rs[3]);
        // entangler RX rotations (layer weights, batch-uniform, LDS broadcast)
        apply_rx<8>(re, im, wc[l * 4 + 0], ws[l * 4 + 0]);
        apply_rx<4>(re, im, wc[l * 4 + 1], ws[l * 4 + 1]);
        apply_rx<2>(re, im, wc[l * 4 + 2], ws[l * 4 + 2]);
        apply_rx<1>(re, im, wc[l * 4 + 3], ws[l * 4 + 3]);
        // ring of CNOTs: (0,1) (1,2) (2,3) (3,0)
        apply_cnot<8, 4>(re, im);
        apply_cnot<4, 2>(re, im);
        apply_cnot<2, 1>(re, im);
        apply_cnot<1, 8>(re, im);
    }

    // ---- probs -> <Z_q> -> linear layer, fused via coef table ----
    float o0 = bsh[0], o1 = bsh[1];
#pragma unroll
    for (int i = 0; i < 16; ++i) {
        float p = re[i] * re[i] + im[i] * im[i];
        o0 = fmaf(p, coef[0][i], o0);
        o1 = fmaf(p, coef[1][i], o1);
    }

    out[b] = make_float2(o0, o1);   // 8B coalesced f32 store
}

extern "C" void kernel_launch(void* const* d_in, const int* in_sizes, int n_in,
                              void* d_out, int out_size, void* d_ws, size_t ws_size,
                              hipStream_t stream) {
    const float* x  = (const float*)d_in[0];
    const float* w  = (const float*)d_in[1];
    const float* Wm = (const float*)d_in[2];
    const float* bv = (const float*)d_in[3];
    float2* out = (float2*)d_out;

    const int B = in_sizes[0] / 4;
    dim3 grid((B + 255) / 256), block(256);
    qdqn_kernel<<<grid, block, 0, stream>>>(x, w, Wm, bv, out, B);
}

// Round 4
// 85.003 us; speedup vs baseline: 1.1566x; 1.1566x over previous
//
#include <hip/hip_runtime.h>

// PIQuantumDQN: 4-qubit, 5-layer re-uploading circuit, B=524288 samples.
// One thread per sample; 16-amplitude complex state in registers.
// wire q (0 = MSB) <-> bit (3-q) of the flat index, so mask(q) = 8 >> q.
// R4: all batch-uniform coefficients live in SGPRs (readfirstlane), no LDS;
// layer 0 built as a tensor product (state is separable until first CNOT);
// epilogue uses a +/- reduction tree for <Z_q> instead of a 32-entry table.

__device__ __forceinline__ float rfl(float v) {
    return __uint_as_float(__builtin_amdgcn_readfirstlane(__float_as_uint(v)));
}

template<int MASK>
__device__ __forceinline__ void apply_ry(float re[16], float im[16], float c, float s) {
#pragma unroll
    for (int i0 = 0; i0 < 16; ++i0) {
        if (i0 & MASK) continue;
        const int i1 = i0 | MASK;
        float r0 = re[i0], r1 = re[i1];
        float m0 = im[i0], m1 = im[i1];
        re[i0] = c * r0 - s * r1;
        re[i1] = s * r0 + c * r1;
        im[i0] = c * m0 - s * m1;
        im[i1] = s * m0 + c * m1;
    }
}

// RX(t): a0' = c*a0 - i*s*a1 ; a1' = -i*s*a0 + c*a1   (c=cos t/2, s=sin t/2)
template<int MASK>
__device__ __forceinline__ void apply_rx(float re[16], float im[16], float c, float s) {
#pragma unroll
    for (int i0 = 0; i0 < 16; ++i0) {
        if (i0 & MASK) continue;
        const int i1 = i0 | MASK;
        float r0 = re[i0], r1 = re[i1];
        float m0 = im[i0], m1 = im[i1];
        re[i0] = c * r0 + s * m1;
        im[i0] = c * m0 - s * r1;
        re[i1] = c * r1 + s * m0;
        im[i1] = c * m1 - s * r0;
    }
}

template<int CMASK, int TMASK>
__device__ __forceinline__ void apply_cnot(float re[16], float im[16]) {
#pragma unroll
    for (int i = 0; i < 16; ++i) {
        if ((i & CMASK) && !(i & TMASK)) {
            const int j = i | TMASK;
            float tr = re[i]; re[i] = re[j]; re[j] = tr;
            float ti = im[i]; im[i] = im[j]; im[j] = ti;
        }
    }
}

__global__ __launch_bounds__(256) void qdqn_kernel(
    const float* __restrict__ x,        // (B,4) fp32
    const float* __restrict__ weights,  // (5,4) fp32
    const float* __restrict__ Wm,       // (2,4) fp32
    const float* __restrict__ bv,       // (2,)  fp32
    float2* __restrict__ out,           // (B,2) fp32
    int B)
{
    // ---- batch-uniform coefficients -> SGPRs (wave-uniform, rfl-pinned) ----
    float wc[20], ws[20];
#pragma unroll
    for (int k = 0; k < 20; ++k) {
        float w = weights[k];               // uniform address -> scalar load
        float s, c;
        __sincosf(0.5f * w, &s, &c);
        wc[k] = rfl(c);
        ws[k] = rfl(s);
    }
    float Wu[8];
#pragma unroll
    for (int k = 0; k < 8; ++k) Wu[k] = rfl(Wm[k]);
    const float b0u = rfl(bv[0]);
    const float b1u = rfl(bv[1]);

    const int b = blockIdx.x * blockDim.x + threadIdx.x;
    if (b >= B) return;

    // ---- load x (16B coalesced), RY half-angle cos/sin (same every layer) ----
    const float4 xraw = ((const float4*)x)[b];
    float xv[4] = { xraw.x, xraw.y, xraw.z, xraw.w };
    const float inv_bounds[4] = { 1.0f / 4.8f, 1.0f / 4.0f, 1.0f / 0.418f, 1.0f / 4.0f };
    const float HALF_PI = 1.57079632679489662f;
    float rc[4], rs[4];
#pragma unroll
    for (int q = 0; q < 4; ++q) {
        float xn = xv[q] * inv_bounds[q];
        xn = fminf(fmaxf(xn, -1.0f), 1.0f);
        __sincosf(xn * HALF_PI, &rs[q], &rc[q]);
    }

    // ---- layer 0 fast path: state separable until the first CNOT ----
    // per wire: RX(w)*RY(a)|0> = (alpha, beta),
    //   alpha = (c_w c_a, -s_w s_a), beta = (c_w s_a, -s_w c_a)
    float ar[4], ai[4], br[4], bi[4];
#pragma unroll
    for (int q = 0; q < 4; ++q) {
        ar[q] =  wc[q] * rc[q];
        ai[q] = -ws[q] * rs[q];
        br[q] =  wc[q] * rs[q];
        bi[q] = -ws[q] * rc[q];
    }
    // tensor product, wire 0 = MSB
    float t2r[4], t2i[4];                     // wires 0,1
#pragma unroll
    for (int i = 0; i < 4; ++i) {
        float xr = (i & 2) ? br[0] : ar[0], xi = (i & 2) ? bi[0] : ai[0];
        float yr = (i & 1) ? br[1] : ar[1], yi = (i & 1) ? bi[1] : ai[1];
        t2r[i] = xr * yr - xi * yi;
        t2i[i] = xr * yi + xi * yr;
    }
    float t3r[8], t3i[8];                     // + wire 2
#pragma unroll
    for (int i = 0; i < 8; ++i) {
        float xr = t2r[i >> 1], xi = t2i[i >> 1];
        float yr = (i & 1) ? br[2] : ar[2], yi = (i & 1) ? bi[2] : ai[2];
        t3r[i] = xr * yr - xi * yi;
        t3i[i] = xr * yi + xi * yr;
    }
    float re[16], im[16];                     // + wire 3
#pragma unroll
    for (int i = 0; i < 16; ++i) {
        float xr = t3r[i >> 1], xi = t3i[i >> 1];
        float yr = (i & 1) ? br[3] : ar[3], yi = (i & 1) ? bi[3] : ai[3];
        re[i] = xr * yr - xi * yi;
        im[i] = xr * yi + xi * yr;
    }
    // layer 0 CNOT ring
    apply_cnot<8, 4>(re, im);
    apply_cnot<4, 2>(re, im);
    apply_cnot<2, 1>(re, im);
    apply_cnot<1, 8>(re, im);

    // ---- layers 1..4 ----
#pragma unroll
    for (int l = 1; l < 5; ++l) {
        apply_ry<8>(re, im, rc[0], rs[0]);
        apply_ry<4>(re, im, rc[1], rs[1]);
        apply_ry<2>(re, im, rc[2], rs[2]);
        apply_ry<1>(re, im, rc[3], rs[3]);
        apply_rx<8>(re, im, wc[l * 4 + 0], ws[l * 4 + 0]);
        apply_rx<4>(re, im, wc[l * 4 + 1], ws[l * 4 + 1]);
        apply_rx<2>(re, im, wc[l * 4 + 2], ws[l * 4 + 2]);
        apply_rx<1>(re, im, wc[l * 4 + 3], ws[l * 4 + 3]);
        apply_cnot<8, 4>(re, im);
        apply_cnot<4, 2>(re, im);
        apply_cnot<2, 1>(re, im);
        apply_cnot<1, 8>(re, im);
    }

    // ---- probs -> <Z_q> via sign tree -> linear layer ----
    float p[16];
#pragma unroll
    for (int i = 0; i < 16; ++i) p[i] = re[i] * re[i] + im[i] * im[i];
    float t[8];
#pragma unroll
    for (int i = 0; i < 8; ++i) t[i] = p[2 * i] + p[2 * i + 1];
    float u[4];
#pragma unroll
    for (int i = 0; i < 4; ++i) u[i] = t[2 * i] + t[2 * i + 1];
    const float v0 = u[0] + u[1], v1 = u[2] + u[3];
    const float z0 = v0 - v1;                                   // wire 0 (bit 3)
    const float z1 = (u[0] - u[1]) + (u[2] - u[3]);             // wire 1 (bit 2)
    const float z2 = (t[0] - t[1]) + (t[2] - t[3])
                   + (t[4] - t[5]) + (t[6] - t[7]);             // wire 2 (bit 1)
    const float z3 = ((p[0] - p[1]) + (p[2] - p[3]))
                   + ((p[4] - p[5]) + (p[6] - p[7]))
                   + ((p[8] - p[9]) + (p[10] - p[11]))
                   + ((p[12] - p[13]) + (p[14] - p[15]));       // wire 3 (bit 0)

    float o0 = b0u, o1 = b1u;
    o0 = fmaf(Wu[0], z0, o0); o0 = fmaf(Wu[1], z1, o0);
    o0 = fmaf(Wu[2], z2, o0); o0 = fmaf(Wu[3], z3, o0);
    o1 = fmaf(Wu[4], z0, o1); o1 = fmaf(Wu[5], z1, o1);
    o1 = fmaf(Wu[6], z2, o1); o1 = fmaf(Wu[7], z3, o1);

    out[b] = make_float2(o0, o1);   // 8B coalesced f32 store
}

extern "C" void kernel_launch(void* const* d_in, const int* in_sizes, int n_in,
                              void* d_out, int out_size, void* d_ws, size_t ws_size,
                              hipStream_t stream) {
    const float* x  = (const float*)d_in[0];
    const float* w  = (const float*)d_in[1];
    const float* Wm = (const float*)d_in[2];
    const float* bv = (const float*)d_in[3];
    float2* out = (float2*)d_out;

    const int B = in_sizes[0] / 4;
    dim3 grid((B + 255) / 256), block(256);
    qdqn_kernel<<<grid, block, 0, stream>>>(x, w, Wm, bv, out, B);
}